// Round 1
// baseline (446.013 us; speedup 1.0000x reference)
//
#include <hip/hip_runtime.h>
#include <math.h>

#define DCOLS 4096
#define TPB   256
#define NJ    4            // float4 loads per thread
#define VPT   16           // values per thread
#define KSEL  64

// Monotone map: larger float <=> larger unsigned
__device__ __forceinline__ unsigned f2ord(float f) {
    unsigned b = __float_as_uint(f);
    return (b & 0x80000000u) ? ~b : (b | 0x80000000u);
}

__global__ __launch_bounds__(TPB) void topk_sigmoid_kernel(
    const float* __restrict__ x, float* __restrict__ out)
{
    const int row = blockIdx.x;
    const int t   = threadIdx.x;
    const float* xr   = x   + (size_t)row * DCOLS;
    float*       outr = out + (size_t)row * DCOLS;

    __shared__ unsigned hist[256];
    __shared__ unsigned s_digit;
    __shared__ unsigned s_remk;
    __shared__ unsigned s_eqcount;
    __shared__ unsigned short eq_list[DCOLS];   // worst-case safe

    // ---- load 16 elements as 4x float4, fully coalesced ----
    float4 v[NJ];
    unsigned u[VPT];
    #pragma unroll
    for (int j = 0; j < NJ; ++j)
        v[j] = reinterpret_cast<const float4*>(xr)[t + TPB * j];
    #pragma unroll
    for (int j = 0; j < NJ; ++j) {
        const float* f = reinterpret_cast<const float*>(&v[j]);
        #pragma unroll
        for (int c = 0; c < 4; ++c)
            u[4*j + c] = f2ord(f[c]);
    }

    // ---- 4-pass radix select, MSB first, 8-bit digits ----
    unsigned pval = 0, pmask = 0, remk = KSEL;
    #pragma unroll
    for (int p = 0; p < 4; ++p) {
        const int shift = 24 - 8 * p;
        hist[t] = 0;
        __syncthreads();
        #pragma unroll
        for (int i = 0; i < VPT; ++i) {
            if ((u[i] & pmask) == pval)
                atomicAdd(&hist[(u[i] >> shift) & 0xFFu], 1u);
        }
        __syncthreads();
        if (t < 64) {                 // wave 0 only: pick the digit
            const int l = t;
            const int bbase = 4 * (63 - l);   // lane 0 owns the top 4 bins
            unsigned c0 = hist[bbase + 0];
            unsigned c1 = hist[bbase + 1];
            unsigned c2 = hist[bbase + 2];
            unsigned c3 = hist[bbase + 3];
            unsigned lsum = c0 + c1 + c2 + c3;
            unsigned incl = lsum;
            #pragma unroll
            for (int o = 1; o < 64; o <<= 1) {
                unsigned n = __shfl_up(incl, o);
                if (l >= o) incl += n;
            }
            unsigned excl = incl - lsum;       // count in bins strictly above this group
            if (excl < remk && remk <= incl) { // boundary inside this lane's group
                unsigned S3 = excl;            // suffix counts above each bin
                unsigned S2 = S3 + c3;
                unsigned S1 = S2 + c2;
                unsigned S0 = S1 + c1;
                int d; unsigned S;
                if      (S3 < remk && remk <= S3 + c3) { d = bbase + 3; S = S3; }
                else if (S2 < remk && remk <= S2 + c2) { d = bbase + 2; S = S2; }
                else if (S1 < remk && remk <= S1 + c1) { d = bbase + 1; S = S1; }
                else                                   { d = bbase + 0; S = S0; }
                s_digit = (unsigned)d;
                s_remk  = remk - S;
            }
        }
        __syncthreads();
        pval  |= s_digit << shift;
        pmask |= 0xFFu   << shift;
        remk   = s_remk;
    }

    // pval == ordered bits of the 64th largest value (T)
    // remk == how many elements equal to T belong in the top-k
    const unsigned Tu = pval;

    if (t == 0) s_eqcount = 0;
    __syncthreads();
    #pragma unroll
    for (int j = 0; j < NJ; ++j) {
        #pragma unroll
        for (int c = 0; c < 4; ++c) {
            const int i = 4*j + c;
            if (u[i] == Tu) {
                unsigned pos = atomicAdd(&s_eqcount, 1u);
                eq_list[pos] = (unsigned short)(4*(t + TPB*j) + c);
            }
        }
    }
    __syncthreads();
    const unsigned E = s_eqcount;

    // ---- emit: sigmoid for selected, 0 otherwise; coalesced float4 stores ----
    #pragma unroll
    for (int j = 0; j < NJ; ++j) {
        float4 o;
        const float* f  = reinterpret_cast<const float*>(&v[j]);
        float*       of = reinterpret_cast<float*>(&o);
        #pragma unroll
        for (int c = 0; c < 4; ++c) {
            const int i = 4*j + c;
            bool inc = false;
            if (u[i] > Tu) {
                inc = true;
            } else if (u[i] == Tu) {
                if (E == remk) {
                    inc = true;              // common case: no boundary tie conflict
                } else {                     // rare: rank equals by ascending index
                    const unsigned gi = 4*(t + TPB*j) + c;
                    unsigned rank = 0;
                    for (unsigned e = 0; e < E; ++e)
                        rank += (eq_list[e] < (unsigned short)gi) ? 1u : 0u;
                    inc = (rank < remk);
                }
            }
            of[c] = inc ? (1.0f / (1.0f + __expf(-f[c]))) : 0.0f;
        }
        reinterpret_cast<float4*>(outr)[t + TPB * j] = o;
    }
}

extern "C" void kernel_launch(void* const* d_in, const int* in_sizes, int n_in,
                              void* d_out, int out_size, void* d_ws, size_t ws_size,
                              hipStream_t stream) {
    const float* x  = (const float*)d_in[0];
    float* out      = (float*)d_out;
    const int nrows = in_sizes[0] / DCOLS;   // 16384
    topk_sigmoid_kernel<<<nrows, TPB, 0, stream>>>(x, out);
}

// Round 2
// 434.283 us; speedup vs baseline: 1.0270x; 1.0270x over previous
//
#include <hip/hip_runtime.h>
#include <math.h>

#define DCOLS 4096
#define TPB   256
#define NJ    4            // float4 loads per thread
#define VPT   16           // values per thread
#define KSEL  64
#define NPIV  5
#define CAP   512          // max candidate-list size for the fast path

// Monotone map: larger float <=> larger unsigned
__device__ __forceinline__ unsigned f2ord(float f) {
    unsigned b = __float_as_uint(f);
    return (b & 0x80000000u) ? ~b : (b | 0x80000000u);
}

// Block-wide sum; s4 is a 4-entry LDS scratch. Two barriers.
__device__ __forceinline__ unsigned block_reduce_sum(unsigned x, unsigned* s4, int t) {
    #pragma unroll
    for (int o = 32; o; o >>= 1) x += __shfl_xor(x, o);
    if ((t & 63) == 0) s4[t >> 6] = x;
    __syncthreads();
    unsigned r = s4[0] + s4[1] + s4[2] + s4[3];
    __syncthreads();
    return r;
}

__global__ __launch_bounds__(TPB) void topk_sigmoid_kernel(
    const float* __restrict__ x, float* __restrict__ out)
{
    const int row  = blockIdx.x;
    const int t    = threadIdx.x;
    const int w    = t >> 6;
    const int lane = t & 63;
    const float* xr   = x   + (size_t)row * DCOLS;
    float*       outr = out + (size_t)row * DCOLS;

    __shared__ unsigned long long cand_key[CAP];
    __shared__ unsigned s_cnt[4 * NPIV];
    __shared__ unsigned s_red[4];
    __shared__ int      s_sel;
    __shared__ unsigned s_top;
    __shared__ unsigned long long s_Tkey;

    const float pivots[NPIV] = {2.6f, 2.3f, 2.0f, 1.7f, 1.4f};

    // ---- load 16 elements as 4x float4, fully coalesced ----
    float fv[VPT];
    unsigned u[VPT];
    #pragma unroll
    for (int j = 0; j < NJ; ++j) {
        float4 v = reinterpret_cast<const float4*>(xr)[t + TPB * j];
        fv[4*j+0] = v.x; fv[4*j+1] = v.y; fv[4*j+2] = v.z; fv[4*j+3] = v.w;
    }
    #pragma unroll
    for (int i = 0; i < VPT; ++i) u[i] = f2ord(fv[i]);

    // ---- count above each pivot (register counters, no LDS traffic) ----
    unsigned cnt[NPIV] = {0, 0, 0, 0, 0};
    #pragma unroll
    for (int i = 0; i < VPT; ++i) {
        #pragma unroll
        for (int p = 0; p < NPIV; ++p)
            cnt[p] += (fv[i] > pivots[p]) ? 1u : 0u;
    }
    #pragma unroll
    for (int p = 0; p < NPIV; ++p) {
        #pragma unroll
        for (int o = 32; o; o >>= 1) cnt[p] += __shfl_xor(cnt[p], o);
    }
    if (lane == 0) {
        #pragma unroll
        for (int p = 0; p < NPIV; ++p) s_cnt[w * NPIV + p] = cnt[p];
    }
    __syncthreads();

    if (t == 0) {
        int sel = -1;
        #pragma unroll
        for (int p = 0; p < NPIV; ++p) {   // highest pivot first -> smallest E
            unsigned c = s_cnt[p] + s_cnt[NPIV + p] + s_cnt[2*NPIV + p] + s_cnt[3*NPIV + p];
            if (c >= KSEL) { sel = (c <= CAP) ? p : -1; break; }
        }
        s_sel = sel;
        s_top = 0;
    }
    __syncthreads();
    const int sel = s_sel;

    if (sel >= 0) {
        // ---- fast path: compact candidates, exact rank-(K-1) selection ----
        const float piv = pivots[sel];
        const unsigned long long lml = (1ull << lane) - 1ull;
        #pragma unroll
        for (int i = 0; i < VPT; ++i) {
            const bool pred = fv[i] > piv;
            const unsigned long long mask = __ballot(pred);
            if (mask) {
                const int leader = (int)__ffsll((long long)mask) - 1;
                unsigned base = 0;
                if (lane == leader) base = atomicAdd(&s_top, (unsigned)__popcll(mask));
                base = (unsigned)__shfl((int)base, leader);
                if (pred) {
                    const unsigned pos = base + (unsigned)__popcll(mask & lml);
                    const unsigned gi  = 4u*t + 1024u*(i >> 2) + (i & 3);
                    cand_key[pos] = ((unsigned long long)u[i] << 32) | (unsigned)(~gi);
                }
            }
        }
        __syncthreads();
        const unsigned E = s_top;   // in [KSEL, CAP]
        for (unsigned jj = t; jj < E; jj += TPB) {
            const unsigned long long mk = cand_key[jj];
            unsigned r = 0;
            for (unsigned e = 0; e < E; ++e)
                r += (cand_key[e] > mk) ? 1u : 0u;   // broadcast LDS reads
            if (r == KSEL - 1) s_Tkey = mk;          // exactly one writer
        }
        __syncthreads();
    } else {
        // ---- exact fallback (arbitrary data): count-based binary search ----
        unsigned long long lo = 0, hi = 0xFFFFFFFFull;
        while (lo < hi) {
            const unsigned mid = (unsigned)((lo + hi + 1ull) >> 1);
            unsigned c = 0;
            #pragma unroll
            for (int i = 0; i < VPT; ++i) c += (u[i] >= mid) ? 1u : 0u;
            c = block_reduce_sum(c, s_red, t);
            if (c >= KSEL) lo = mid; else hi = mid - 1ull;
        }
        const unsigned Tu = (unsigned)lo;
        unsigned cgt = 0;
        #pragma unroll
        for (int i = 0; i < VPT; ++i) cgt += (u[i] > Tu) ? 1u : 0u;
        cgt = block_reduce_sum(cgt, s_red, t);
        const unsigned remk = KSEL - cgt;           // in [1, KSEL]
        unsigned ilo = 0, ihi = DCOLS - 1;
        while (ilo < ihi) {
            const unsigned mid = (ilo + ihi) >> 1;
            unsigned c = 0;
            #pragma unroll
            for (int i = 0; i < VPT; ++i) {
                const unsigned gi = 4u*t + 1024u*(i >> 2) + (i & 3);
                c += (u[i] == Tu && gi <= mid) ? 1u : 0u;
            }
            c = block_reduce_sum(c, s_red, t);
            if (c >= remk) ihi = mid; else ilo = mid + 1;
        }
        if (t == 0) s_Tkey = ((unsigned long long)Tu << 32) | (unsigned)(~ilo);
        __syncthreads();
    }

    // ---- emit: include iff (u, idx-order) key >= threshold key ----
    const unsigned long long Tkey = s_Tkey;
    #pragma unroll
    for (int j = 0; j < NJ; ++j) {
        float4 o;
        float* of = reinterpret_cast<float*>(&o);
        #pragma unroll
        for (int c = 0; c < 4; ++c) {
            const int i = 4*j + c;
            const unsigned gi = 4u*t + 1024u*j + c;
            const unsigned long long key =
                ((unsigned long long)u[i] << 32) | (unsigned)(~gi);
            const float sig = 1.0f / (1.0f + __expf(-fv[i]));
            of[c] = (key >= Tkey) ? sig : 0.0f;
        }
        reinterpret_cast<float4*>(outr)[t + TPB * j] = o;
    }
}

extern "C" void kernel_launch(void* const* d_in, const int* in_sizes, int n_in,
                              void* d_out, int out_size, void* d_ws, size_t ws_size,
                              hipStream_t stream) {
    const float* x  = (const float*)d_in[0];
    float* out      = (float*)d_out;
    const int nrows = in_sizes[0] / DCOLS;   // 16384
    topk_sigmoid_kernel<<<nrows, TPB, 0, stream>>>(x, out);
}